// Round 6
// baseline (1553.727 us; speedup 1.0000x reference)
//
#include <hip/hip_runtime.h>

#define D128 128
#define NT 101
#define NHI 37              // NT - 64
#define TDEC 512
#define PSTR 112            // padded p row: 4 quarters of 28 floats (16B aligned)

// ---- decode LDS layout (floats) ----
#define KP2T_OFF 0                       // [128][101] kp2 col-major (stride 101)
#define KT2_OFF  (KP2T_OFF + D128*NT)    // [128][37]  K rows 64..100 (stride 37)
#define P_OFF    (KT2_OFF + D128*NHI)    // 8 x PSTR   (zero-padded tails)
#define LGH_OFF  (P_OFF + 8*PSTR)        // 8 x 104 logit partials
#define O_OFFS   (LGH_OFF + 8*104)       // 128
#define QV_OFF   (O_OFFS + 128)          // 128   raw QA row of current selection
#define DM_OFF   (QV_OFF + 128)          // 104   demand
#define LDS_FLOATS (DM_OFF + 104)        // 19752 floats = 79008 B -> 2 WG/CU

#define INV_D_CONST 0.08838834764831845f

__device__ __forceinline__ int read_scalar_int(const void* p){
    unsigned u = *(const unsigned*)p;
    if (u < 1000000u) return (int)u;
    return (int)__uint_as_float(u);
}
__device__ __forceinline__ float read_scalar_float(const void* p){
    unsigned u = *(const unsigned*)p;
    if (u < 1000000u) return (float)(int)u;
    return __uint_as_float(u);
}

// ---- DPP cross-lane helpers (VALU pipe, no DS) ----
template<int C> __device__ __forceinline__ float dppf(float x){
    return __int_as_float(__builtin_amdgcn_update_dpp(
        __float_as_int(x), __float_as_int(x), C, 0xF, 0xF, false));
}
template<int C> __device__ __forceinline__ int dppi(int x){
    return __builtin_amdgcn_update_dpp(x, x, C, 0xF, 0xF, false);
}
__device__ __forceinline__ float wave_sum64(float v){
    v += dppf<0xB1>(v); v += dppf<0x4E>(v); v += dppf<0x141>(v); v += dppf<0x140>(v);
    v += __shfl_xor(v, 16, 64); v += __shfl_xor(v, 32, 64); return v;
}
__device__ __forceinline__ float wave_max64(float v){
    v = fmaxf(v, dppf<0xB1>(v)); v = fmaxf(v, dppf<0x4E>(v));
    v = fmaxf(v, dppf<0x141>(v)); v = fmaxf(v, dppf<0x140>(v));
    v = fmaxf(v, __shfl_xor(v, 16, 64)); v = fmaxf(v, __shfl_xor(v, 32, 64)); return v;
}
__device__ __forceinline__ void wave_argmax64(float& v, int& i){
    { float ov = dppf<0xB1>(v);        int oi = dppi<0xB1>(i);        if (ov>v || (ov==v && oi<i)){v=ov;i=oi;} }
    { float ov = dppf<0x4E>(v);        int oi = dppi<0x4E>(i);        if (ov>v || (ov==v && oi<i)){v=ov;i=oi;} }
    { float ov = dppf<0x141>(v);       int oi = dppi<0x141>(i);       if (ov>v || (ov==v && oi<i)){v=ov;i=oi;} }
    { float ov = dppf<0x140>(v);       int oi = dppi<0x140>(i);       if (ov>v || (ov==v && oi<i)){v=ov;i=oi;} }
    { float ov = __shfl_xor(v,16,64);  int oi = __shfl_xor(i,16,64);  if (ov>v || (ov==v && oi<i)){v=ov;i=oi;} }
    { float ov = __shfl_xor(v,32,64);  int oi = __shfl_xor(i,32,64);  if (ov>v || (ov==v && oi<i)){v=ov;i=oi;} }
}

// ---------------- weight folding (unchanged) ----------------
__global__ __launch_bounds__(512) void prep_w2(
        const float* __restrict__ fc_w, const float* __restrict__ attn_w,
        const float* __restrict__ prob_k, const float* __restrict__ attn_fc,
        const float* __restrict__ attn_k, const float* __restrict__ attn_v,
        float* __restrict__ Wcat, float* __restrict__ wlast){
    int i = blockIdx.x, t = threadIdx.x;
    if (i < 128){
        if (t < 128){
            Wcat[i*512 + t] = attn_k[i*D128 + t];
        } else if (t < 256){
            int j = t - 128;
            Wcat[i*512 + 128 + j] = attn_v[i*D128 + j];
        } else if (t < 384){
            int j = t - 256; float acc = 0.f;
            for (int e = 0; e < D128; ++e) acc += prob_k[i*D128+e]*attn_fc[j*D128+e];
            Wcat[i*512 + 256 + j] = acc;
        } else {
            int j = t - 384; float acc = 0.f;
            for (int e = 0; e < D128; ++e) acc += fc_w[i*D128+e]*attn_w[e*D128+j];
            Wcat[i*512 + 384 + j] = acc;
        }
    } else if (t < 128){
        float acc = 0.f;
        for (int e = 0; e < D128; ++e) acc += fc_w[128*D128+e]*attn_w[e*D128+t];
        wlast[t] = acc;
    }
}

__global__ __launch_bounds__(128) void prep_pq(
        const float* __restrict__ pool, const float* __restrict__ fc1_w,
        const float* __restrict__ attn_w, float* __restrict__ pq){
    __shared__ float s1[128], s2[128];
    int b = blockIdx.x, t = threadIdx.x;
    s1[t] = pool[(size_t)b*D128 + t];
    __syncthreads();
    float a = 0.f;
    for (int i = 0; i < D128; ++i) a += s1[i]*fc1_w[i*D128 + t];
    s2[t] = a;
    __syncthreads();
    float a2 = 0.f;
    for (int i = 0; i < D128; ++i) a2 += s2[i]*attn_w[i*D128 + t];
    pq[(size_t)b*D128 + t] = a2;
}

__global__ __launch_bounds__(256) void gemm_prep(
        const float* __restrict__ enc, const float* __restrict__ Wcat,
        const float* __restrict__ pq, int M,
        float* __restrict__ KVP, float* __restrict__ QA){
    __shared__ float As[64*132];
    const int t = threadIdx.x;
    const int m0 = blockIdx.x * 64;
    const int cb0 = blockIdx.y * 64;
    for (int i = t; i < 64*32; i += 256){
        int row = i >> 5, c4 = (i & 31) << 2;
        float4 val = make_float4(0.f,0.f,0.f,0.f);
        if (m0 + row < M) val = *(const float4*)(enc + (size_t)(m0+row)*D128 + c4);
        *(float4*)&As[row*132 + c4] = val;
    }
    __syncthreads();
    const int tx = t & 15, ty = t >> 4;
    float acc[4][4];
    #pragma unroll
    for (int i = 0; i < 4; ++i)
        #pragma unroll
        for (int j = 0; j < 4; ++j) acc[i][j] = 0.f;
    const float* wp = Wcat + cb0 + tx*4;
    #pragma unroll 4
    for (int k = 0; k < 128; ++k){
        float4 bv = *(const float4*)(wp + (size_t)k*512);
        float a0 = As[(ty*4+0)*132 + k];
        float a1 = As[(ty*4+1)*132 + k];
        float a2 = As[(ty*4+2)*132 + k];
        float a3 = As[(ty*4+3)*132 + k];
        acc[0][0] += a0*bv.x; acc[0][1] += a0*bv.y; acc[0][2] += a0*bv.z; acc[0][3] += a0*bv.w;
        acc[1][0] += a1*bv.x; acc[1][1] += a1*bv.y; acc[1][2] += a1*bv.z; acc[1][3] += a1*bv.w;
        acc[2][0] += a2*bv.x; acc[2][1] += a2*bv.y; acc[2][2] += a2*bv.z; acc[2][3] += a2*bv.w;
        acc[3][0] += a3*bv.x; acc[3][1] += a3*bv.y; acc[3][2] += a3*bv.z; acc[3][3] += a3*bv.w;
    }
    #pragma unroll
    for (int rr = 0; rr < 4; ++rr){
        int m = m0 + ty*4 + rr;
        if (m >= M) continue;
        if (cb0 < 384){
            *(float4*)&KVP[(size_t)m*384 + cb0 + tx*4] =
                make_float4(acc[rr][0], acc[rr][1], acc[rr][2], acc[rr][3]);
        } else {
            int bb = m / NT;
            int c = cb0 - 384 + tx*4;
            float4 pv = *(const float4*)(pq + (size_t)bb*D128 + c);
            *(float4*)&QA[(size_t)m*D128 + c] =
                make_float4(acc[rr][0]+pv.x, acc[rr][1]+pv.y, acc[rr][2]+pv.z, acc[rr][3]+pv.w);
        }
    }
}

// ---------------- sequential decode: 8 waves per batch elem, 2 barriers/step ----------------
// Register budget designed for the compiler's observed 64-VGPR cap on 512-thread
// blocks: only k0[16] + vv[28] + scalar state live in registers; K rows 64-100,
// kp2, demand live in LDS with odd strides (2-way bank aliasing = free).
__global__ __attribute__((amdgpu_flat_work_group_size(TDEC, TDEC), amdgpu_waves_per_eu(4)))
void decode(
    const float* __restrict__ QA, const float* __restrict__ KVP,
    const float* __restrict__ wlast, const float* __restrict__ demand,
    const float* __restrict__ capv, const void* p_nd, const void* p_temp,
    int n_steps, float* __restrict__ out)
{
    __shared__ float sm[LDS_FLOATS];
    const int b = blockIdx.x, t = threadIdx.x;
    const int l = t & 63, g = t >> 6;          // lane, wave (= head = dim-block)
    const int qq = l >> 4, d16 = l & 15;       // PV mapping
    const int nd = read_scalar_int(p_nd);
    const float temp = read_scalar_float(p_temp);
    const float capfull = capv[0];
    float dyn = capv[b];
    const long mb = (long)b * NT;
    const bool hasB = (l < NHI);               // second-row validity (l < 37)

    // ---- k0: K row l (head g) in registers ----
    float k0[16];
    {
        const float* kr = KVP + (mb + l)*384 + g*16;
        #pragma unroll
        for (int j4 = 0; j4 < 4; ++j4){
            float4 a = *(const float4*)(kr + j4*4);
            k0[j4*4+0]=a.x; k0[j4*4+1]=a.y; k0[j4*4+2]=a.z; k0[j4*4+3]=a.w;
        }
    }
    float kwl1 = 0.f;
    #pragma unroll
    for (int j = 0; j < 16; ++j) kwl1 += wlast[g*16 + j]*k0[j];
    // kwl2 from K row l+64 (streamed, not kept)
    float kwl2 = 0.f;
    if (hasB){
        const float* kr = KVP + (mb + l + 64)*384 + g*16;
        #pragma unroll
        for (int j4 = 0; j4 < 4; ++j4){
            float4 a = *(const float4*)(kr + j4*4);
            kwl2 += wlast[g*16+j4*4+0]*a.x + wlast[g*16+j4*4+1]*a.y
                  + wlast[g*16+j4*4+2]*a.z + wlast[g*16+j4*4+3]*a.w;
        }
    }
    // ---- vv: V column slice (dim d16 of head g, n = qq*28 + i) in registers ----
    float vv[28];
    #pragma unroll
    for (int i = 0; i < 28; ++i){
        int n = qq*28 + i;
        vv[i] = (n < NT) ? KVP[(mb + n)*384 + 128 + g*16 + d16] : 0.f;
    }
    // ---- stage KP2T [d][n] (stride 101) ----
    for (int i = t; i < NT*D128; i += TDEC){
        int n = i >> 7, d = i & 127;
        sm[KP2T_OFF + d*NT + n] = KVP[(mb + n)*384 + 256 + d];
    }
    // ---- stage KT2 [d][r] = K rows 64..100 (stride 37) ----
    for (int i = t; i < NHI*D128; i += TDEC){
        int d = i / NHI, r = i - d*NHI;
        sm[KT2_OFF + d*NHI + r] = KVP[(mb + 64 + r)*384 + d];
    }
    // ---- demand, P pads, initial QV (index0 = 0) ----
    if (t < 104) sm[DM_OFF + t] = (t < NT) ? demand[mb + t] : 0.f;
    for (int i = t; i < 8*PSTR; i += TDEC) sm[P_OFF + i] = 0.f;
    if (t >= 384) sm[QV_OFF + (t - 384)] = QA[mb*D128 + (t - 384)];
    __syncthreads();

    // ---- mask registers (redundant across waves) ----
    float mk1a = 0.f, mk1b = 0.f;
    float m1 = (l < nd) ? 1.f : ((sm[DM_OFF + l] > dyn) ? 1.f : 0.f);
    float m2 = ((l + 64) < nd) ? 1.f : ((hasB && sm[DM_OFF + 64 + l] > dyn) ? 1.f : 0.f);
    int served = 0; float logps = 0.f;

    for (int s = 0; s < n_steps; ++s){
        // ==== P1: compat -> softmax -> PV (wave-internal, no barrier) ====
        float qk1 = 0.f, qk2 = 0.f;
        {
            const float4* qp = (const float4*)&sm[QV_OFF + g*16];
            #pragma unroll
            for (int j4 = 0; j4 < 4; ++j4){
                float4 q4 = qp[j4];
                qk1 += q4.x*k0[j4*4+0] + q4.y*k0[j4*4+1] + q4.z*k0[j4*4+2] + q4.w*k0[j4*4+3];
                if (hasB){
                    const float* kt = &sm[KT2_OFF + (g*16 + j4*4)*NHI + l];
                    qk2 += q4.x*kt[0] + q4.y*kt[NHI] + q4.z*kt[2*NHI] + q4.w*kt[3*NHI];
                }
            }
        }
        float c1 = 0.25f*(qk1 + dyn*kwl1);
        if (m1 > 0.f) c1 = -1000000000.0f;
        float c2 = -1000000000.0f;
        if (hasB){
            float a = 0.25f*(qk2 + dyn*kwl2);
            c2 = (m2 > 0.f) ? -1000000000.0f : a;
        }
        float mx = wave_max64(fmaxf(c1, c2));
        float p1 = expf(c1 - mx);
        float p2v = hasB ? expf(c2 - mx) : 0.f;
        float ls = wave_sum64(p1 + p2v);
        sm[P_OFF + g*PSTR + l] = p1;
        if (hasB) sm[P_OFF + g*PSTR + 64 + l] = p2v;
        // same-wave DS ordering: write->read needs no __syncthreads
        float acc = 0.f;
        {
            const float4* pp = (const float4*)&sm[P_OFF + g*PSTR + qq*28];
            #pragma unroll
            for (int i4 = 0; i4 < 7; ++i4){
                float4 pv = pp[i4];
                acc += pv.x*vv[i4*4+0] + pv.y*vv[i4*4+1] + pv.z*vv[i4*4+2] + pv.w*vv[i4*4+3];
            }
        }
        acc += __shfl_xor(acc, 16, 64);
        acc += __shfl_xor(acc, 32, 64);
        if (l < 16) sm[O_OFFS + g*16 + l] = acc / ls;

        // ==== P2: logit partials for dim-block g (kp2 from LDS columns) ====
        float lg1 = 0.f, lg2 = 0.f;
        {
            const float4* op = (const float4*)&sm[O_OFFS + g*16];
            #pragma unroll
            for (int j4 = 0; j4 < 4; ++j4){
                float4 o4 = op[j4];
                const float* kpj = &sm[KP2T_OFF + (g*16 + j4*4)*NT + l];
                lg1 += o4.x*kpj[0]  + o4.y*kpj[NT]    + o4.z*kpj[2*NT]    + o4.w*kpj[3*NT];
                lg2 += o4.x*kpj[64] + o4.y*kpj[NT+64] + o4.z*kpj[2*NT+64] + o4.w*kpj[3*NT+64];
            }
        }
        sm[LGH_OFF + g*104 + l] = lg1;
        if (hasB) sm[LGH_OFF + g*104 + 64 + l] = lg2;
        __syncthreads();                                   // B

        // ==== F: raw-score argmax (tanh monotone -> same winner), redundant per wave ====
        float s1v = 0.f;
        #pragma unroll
        for (int w = 0; w < 8; ++w) s1v += sm[LGH_OFF + w*104 + l];
        float s2v = 0.f;
        if (hasB){
            #pragma unroll
            for (int w = 0; w < 8; ++w) s2v += sm[LGH_OFF + w*104 + 64 + l];
        }
        float r1 = (m1 > 0.f) ? -3.0e38f : s1v;
        float r2 = hasB ? ((m2 > 0.f) ? -3.0e38f : s2v) : -3.3e38f;
        float bv = r1; int bix = l;
        if (r2 > bv){ bv = r2; bix = l + 64; }
        wave_argmax64(bv, bix);
        // QA row fetch for next step (waves 6,7): issue early, write QV before C
        float qreg = 0.f;
        if (t >= 384) qreg = QA[(mb + bix)*D128 + (t - 384)];
        // save pre-update state for wave0's shadow lse
        float m1o = m1, m2o = m2;
        bool keep_lp = (served < NT - 1);
        // bookkeeping (redundant, wave-uniform)
        float selv = sm[DM_OFF + bix];
        float vis  = (bix < 64) ? __shfl(mk1a, bix, 64) : __shfl(mk1b, bix - 64, 64);
        bool go = bix < nd;
        float dynN = go ? capfull : (dyn - selv);
        if (!go && vis == 0.f) served++;
        if (bix == l && l >= nd) mk1a = 1.f;
        if (hasB && bix == (l + 64)) mk1b = 1.f;
        bool done = served >= NT - nd;
        float depotf = (go && !done) ? 1.f : 0.f;
        dyn = dynN;
        m1 = fmaxf(mk1a, (sm[DM_OFF + l] > dyn) ? 1.f : 0.f);
        if (l < nd) m1 = depotf;
        m2 = fmaxf(mk1b, (hasB && sm[DM_OFF + 64 + l] > dyn) ? 1.f : 0.f);
        if ((l + 64) < nd) m2 = depotf;
        if (t >= 384) sm[QV_OFF + (t - 384)] = qreg;
        if (g == 0 && l == 0) out[(size_t)b*n_steps + s] = (float)bix;
        __syncthreads();                                   // C

        // ==== wave 0 shadow: true logits -> lse -> logp (hidden under other waves' P1) ====
        if (g == 0){
            float Lm = tanhf(bv * INV_D_CONST) * 10.0f / temp;
            float L1 = (m1o > 0.f) ? (-1000000000.0f / temp)
                                   : (tanhf(s1v * INV_D_CONST) * 10.0f / temp);
            float e1 = expf(L1 - Lm);
            float e2 = 0.f;
            if (hasB){
                float L2 = (m2o > 0.f) ? (-1000000000.0f / temp)
                                       : (tanhf(s2v * INV_D_CONST) * 10.0f / temp);
                e2 = expf(L2 - Lm);
            }
            float ss = wave_sum64(e1 + e2);
            if (keep_lp) logps += -logf(ss);
        }
    }
    if (t == 0) out[(size_t)gridDim.x*n_steps + b] = logps;
}

extern "C" void kernel_launch(void* const* d_in, const int* in_sizes, int n_in,
                              void* d_out, int out_size, void* d_ws, size_t ws_size,
                              hipStream_t stream) {
    const float* enc     = (const float*)d_in[0];
    const float* pool    = (const float*)d_in[1];
    const float* capv    = (const float*)d_in[2];
    const float* demand  = (const float*)d_in[3];
    const float* fc_w    = (const float*)d_in[4];
    const float* fc1_w   = (const float*)d_in[5];
    const float* attn_w  = (const float*)d_in[6];
    const float* attn_k  = (const float*)d_in[7];
    const float* attn_v  = (const float*)d_in[8];
    const float* attn_fc = (const float*)d_in[9];
    const float* prob_k  = (const float*)d_in[10];
    const void*  p_nd    = d_in[12];
    const void*  p_temp  = d_in[13];

    int B = in_sizes[1] / D128;          // pool is (B, D)
    int n_steps = out_size / B - 1;      // out = B*n_steps actions + B logps
    int M = B * NT;

    float* ws    = (float*)d_ws;
    float* Wcat  = ws;                               // 128*512
    float* wlast = Wcat + 128*512;                   // 128
    float* pq    = wlast + 128;                      // B*128
    float* KVP   = pq + (size_t)B*D128;              // M*384
    float* QA    = KVP + (size_t)M*384;              // M*128

    prep_w2<<<129, 512, 0, stream>>>(fc_w, attn_w, prob_k, attn_fc, attn_k, attn_v, Wcat, wlast);
    prep_pq<<<B, 128, 0, stream>>>(pool, fc1_w, attn_w, pq);
    dim3 ggrid((M + 63)/64, 8);
    gemm_prep<<<ggrid, 256, 0, stream>>>(enc, Wcat, pq, M, KVP, QA);

    decode<<<B, TDEC, 0, stream>>>(QA, KVP, wlast, demand, capv, p_nd, p_temp,
                                   n_steps, (float*)d_out);
}

// Round 7
// 1167.863 us; speedup vs baseline: 1.3304x; 1.3304x over previous
//
#include <hip/hip_runtime.h>

#define D128 128
#define NT 101
#define TDEC 512
#define PSTR 112            // padded p row: 4 quarters of 28 floats (16B aligned)
#define VPITCH 17           // VH inner stride (odd -> 2-way bank aliasing, free)
#define VGPP (112*VPITCH)   // per-head VH pitch = 1904 floats

// ---- decode LDS layout (floats) ----
#define VH_OFF   0                       // [8][112][17] V slices (zero-padded rows)
#define P_OFF    (VH_OFF + 8*VGPP)       // 8 x PSTR
#define LGH_OFF  (P_OFF + 8*PSTR)        // 8 x 104 logit partials
#define O_OFFS   (LGH_OFF + 8*104)       // 128
#define QV_OFF   (O_OFFS + 128)          // 128  raw QA row of current selection
#define LDS_FLOATS (QV_OFF + 128)        // 17216 floats = 68,864 B -> 2 WG/CU

#define INV_D_CONST 0.08838834764831845f

__device__ __forceinline__ int read_scalar_int(const void* p){
    unsigned u = *(const unsigned*)p;
    if (u < 1000000u) return (int)u;
    return (int)__uint_as_float(u);
}
__device__ __forceinline__ float read_scalar_float(const void* p){
    unsigned u = *(const unsigned*)p;
    if (u < 1000000u) return (float)(int)u;
    return __uint_as_float(u);
}

// ---- DPP cross-lane helpers (VALU pipe, no DS) ----
template<int C> __device__ __forceinline__ float dppf(float x){
    return __int_as_float(__builtin_amdgcn_update_dpp(
        __float_as_int(x), __float_as_int(x), C, 0xF, 0xF, false));
}
template<int C> __device__ __forceinline__ int dppi(int x){
    return __builtin_amdgcn_update_dpp(x, x, C, 0xF, 0xF, false);
}
__device__ __forceinline__ float wave_sum64(float v){
    v += dppf<0xB1>(v); v += dppf<0x4E>(v); v += dppf<0x141>(v); v += dppf<0x140>(v);
    v += __shfl_xor(v, 16, 64); v += __shfl_xor(v, 32, 64); return v;
}
__device__ __forceinline__ float wave_max64(float v){
    v = fmaxf(v, dppf<0xB1>(v)); v = fmaxf(v, dppf<0x4E>(v));
    v = fmaxf(v, dppf<0x141>(v)); v = fmaxf(v, dppf<0x140>(v));
    v = fmaxf(v, __shfl_xor(v, 16, 64)); v = fmaxf(v, __shfl_xor(v, 32, 64)); return v;
}
__device__ __forceinline__ void wave_argmax64(float& v, int& i){
    { float ov = dppf<0xB1>(v);        int oi = dppi<0xB1>(i);        if (ov>v || (ov==v && oi<i)){v=ov;i=oi;} }
    { float ov = dppf<0x4E>(v);        int oi = dppi<0x4E>(i);        if (ov>v || (ov==v && oi<i)){v=ov;i=oi;} }
    { float ov = dppf<0x141>(v);       int oi = dppi<0x141>(i);       if (ov>v || (ov==v && oi<i)){v=ov;i=oi;} }
    { float ov = dppf<0x140>(v);       int oi = dppi<0x140>(i);       if (ov>v || (ov==v && oi<i)){v=ov;i=oi;} }
    { float ov = __shfl_xor(v,16,64);  int oi = __shfl_xor(i,16,64);  if (ov>v || (ov==v && oi<i)){v=ov;i=oi;} }
    { float ov = __shfl_xor(v,32,64);  int oi = __shfl_xor(i,32,64);  if (ov>v || (ov==v && oi<i)){v=ov;i=oi;} }
}

// ---------------- weight folding (unchanged) ----------------
__global__ __launch_bounds__(512) void prep_w2(
        const float* __restrict__ fc_w, const float* __restrict__ attn_w,
        const float* __restrict__ prob_k, const float* __restrict__ attn_fc,
        const float* __restrict__ attn_k, const float* __restrict__ attn_v,
        float* __restrict__ Wcat, float* __restrict__ wlast){
    int i = blockIdx.x, t = threadIdx.x;
    if (i < 128){
        if (t < 128){
            Wcat[i*512 + t] = attn_k[i*D128 + t];
        } else if (t < 256){
            int j = t - 128;
            Wcat[i*512 + 128 + j] = attn_v[i*D128 + j];
        } else if (t < 384){
            int j = t - 256; float acc = 0.f;
            for (int e = 0; e < D128; ++e) acc += prob_k[i*D128+e]*attn_fc[j*D128+e];
            Wcat[i*512 + 256 + j] = acc;
        } else {
            int j = t - 384; float acc = 0.f;
            for (int e = 0; e < D128; ++e) acc += fc_w[i*D128+e]*attn_w[e*D128+j];
            Wcat[i*512 + 384 + j] = acc;
        }
    } else if (t < 128){
        float acc = 0.f;
        for (int e = 0; e < D128; ++e) acc += fc_w[128*D128+e]*attn_w[e*D128+t];
        wlast[t] = acc;
    }
}

__global__ __launch_bounds__(128) void prep_pq(
        const float* __restrict__ pool, const float* __restrict__ fc1_w,
        const float* __restrict__ attn_w, float* __restrict__ pq){
    __shared__ float s1[128], s2[128];
    int b = blockIdx.x, t = threadIdx.x;
    s1[t] = pool[(size_t)b*D128 + t];
    __syncthreads();
    float a = 0.f;
    for (int i = 0; i < D128; ++i) a += s1[i]*fc1_w[i*D128 + t];
    s2[t] = a;
    __syncthreads();
    float a2 = 0.f;
    for (int i = 0; i < D128; ++i) a2 += s2[i]*attn_w[i*D128 + t];
    pq[(size_t)b*D128 + t] = a2;
}

__global__ __launch_bounds__(256) void gemm_prep(
        const float* __restrict__ enc, const float* __restrict__ Wcat,
        const float* __restrict__ pq, int M,
        float* __restrict__ KVP, float* __restrict__ QA){
    __shared__ float As[64*132];
    const int t = threadIdx.x;
    const int m0 = blockIdx.x * 64;
    const int cb0 = blockIdx.y * 64;
    for (int i = t; i < 64*32; i += 256){
        int row = i >> 5, c4 = (i & 31) << 2;
        float4 val = make_float4(0.f,0.f,0.f,0.f);
        if (m0 + row < M) val = *(const float4*)(enc + (size_t)(m0+row)*D128 + c4);
        *(float4*)&As[row*132 + c4] = val;
    }
    __syncthreads();
    const int tx = t & 15, ty = t >> 4;
    float acc[4][4];
    #pragma unroll
    for (int i = 0; i < 4; ++i)
        #pragma unroll
        for (int j = 0; j < 4; ++j) acc[i][j] = 0.f;
    const float* wp = Wcat + cb0 + tx*4;
    #pragma unroll 4
    for (int k = 0; k < 128; ++k){
        float4 bv = *(const float4*)(wp + (size_t)k*512);
        float a0 = As[(ty*4+0)*132 + k];
        float a1 = As[(ty*4+1)*132 + k];
        float a2 = As[(ty*4+2)*132 + k];
        float a3 = As[(ty*4+3)*132 + k];
        acc[0][0] += a0*bv.x; acc[0][1] += a0*bv.y; acc[0][2] += a0*bv.z; acc[0][3] += a0*bv.w;
        acc[1][0] += a1*bv.x; acc[1][1] += a1*bv.y; acc[1][2] += a1*bv.z; acc[1][3] += a1*bv.w;
        acc[2][0] += a2*bv.x; acc[2][1] += a2*bv.y; acc[2][2] += a2*bv.z; acc[2][3] += a2*bv.w;
        acc[3][0] += a3*bv.x; acc[3][1] += a3*bv.y; acc[3][2] += a3*bv.z; acc[3][3] += a3*bv.w;
    }
    #pragma unroll
    for (int rr = 0; rr < 4; ++rr){
        int m = m0 + ty*4 + rr;
        if (m >= M) continue;
        if (cb0 < 384){
            *(float4*)&KVP[(size_t)m*384 + cb0 + tx*4] =
                make_float4(acc[rr][0], acc[rr][1], acc[rr][2], acc[rr][3]);
        } else {
            int bb = m / NT;
            int c = cb0 - 384 + tx*4;
            float4 pv = *(const float4*)(pq + (size_t)bb*D128 + c);
            *(float4*)&QA[(size_t)m*D128 + c] =
                make_float4(acc[rr][0]+pv.x, acc[rr][1]+pv.y, acc[rr][2]+pv.z, acc[rr][3]+pv.w);
        }
    }
}

// ---------------- sequential decode: 8 waves per batch elem, 2 barriers/step ----------------
// Register plan: k0/k1 (K rows) + p2a/p2b (kp2 rows) = 64 floats hot in regs;
// V slice in LDS VH (stride-17 rows -> PV reads are 2-way bank-aliased, free);
// amdgpu_num_vgpr(128) requests the VGPR budget the data needs (observed: the
// default allocator pins 512-thread kernels at 64 VGPR and spills ~45 regs).
__global__ __attribute__((amdgpu_flat_work_group_size(TDEC, TDEC), amdgpu_num_vgpr(128)))
void decode(
    const float* __restrict__ QA, const float* __restrict__ KVP,
    const float* __restrict__ wlast, const float* __restrict__ demand,
    const float* __restrict__ capv, const void* p_nd, const void* p_temp,
    int n_steps, float* __restrict__ out)
{
    __shared__ float sm[LDS_FLOATS];
    const int b = blockIdx.x, t = threadIdx.x;
    const int l = t & 63, g = t >> 6;          // lane, wave (= head = dim-block)
    const int qq = l >> 4, d16 = l & 15;       // PV mapping
    const int nd = read_scalar_int(p_nd);
    const float temp = read_scalar_float(p_temp);
    const float capfull = capv[0];
    float dyn = capv[b];
    const long mb = (long)b * NT;
    const bool hasB = (l < NT - 64);           // second-row validity (l < 37)

    // ---- K rows (head g) for n = l, l+64 ----
    float k0[16], k1[16];
    {
        const float* kr = KVP + (mb + l)*384 + g*16;
        #pragma unroll
        for (int j4 = 0; j4 < 4; ++j4){
            float4 a = *(const float4*)(kr + j4*4);
            k0[j4*4+0]=a.x; k0[j4*4+1]=a.y; k0[j4*4+2]=a.z; k0[j4*4+3]=a.w;
        }
    }
    if (hasB){
        const float* kr = KVP + (mb + l + 64)*384 + g*16;
        #pragma unroll
        for (int j4 = 0; j4 < 4; ++j4){
            float4 a = *(const float4*)(kr + j4*4);
            k1[j4*4+0]=a.x; k1[j4*4+1]=a.y; k1[j4*4+2]=a.z; k1[j4*4+3]=a.w;
        }
    } else {
        #pragma unroll
        for (int j = 0; j < 16; ++j) k1[j] = 0.f;
    }
    float kwl1 = 0.f, kwl2 = 0.f;
    #pragma unroll
    for (int j = 0; j < 16; ++j){
        float w = wlast[g*16 + j];
        kwl1 += w*k0[j]; kwl2 += w*k1[j];
    }
    // ---- kp2 rows (dims 16g..16g+16) for n = l, l+64 ----
    float p2a[16], p2b[16];
    {
        const float* kr = KVP + (mb + l)*384 + 256 + g*16;
        #pragma unroll
        for (int j4 = 0; j4 < 4; ++j4){
            float4 a = *(const float4*)(kr + j4*4);
            p2a[j4*4+0]=a.x; p2a[j4*4+1]=a.y; p2a[j4*4+2]=a.z; p2a[j4*4+3]=a.w;
        }
    }
    if (hasB){
        const float* kr = KVP + (mb + l + 64)*384 + 256 + g*16;
        #pragma unroll
        for (int j4 = 0; j4 < 4; ++j4){
            float4 a = *(const float4*)(kr + j4*4);
            p2b[j4*4+0]=a.x; p2b[j4*4+1]=a.y; p2b[j4*4+2]=a.z; p2b[j4*4+3]=a.w;
        }
    } else {
        #pragma unroll
        for (int j = 0; j < 16; ++j) p2b[j] = 0.f;
    }
    // ---- demand + mask registers (redundant across waves) ----
    float dem1 = demand[mb + l];
    float dem2 = hasB ? demand[mb + l + 64] : 0.f;
    float mk1a = 0.f, mk1b = 0.f;
    float m1 = (l < nd) ? 1.f : ((dem1 > dyn) ? 1.f : 0.f);
    float m2 = ((l + 64) < nd) ? 1.f : ((dem2 > dyn) ? 1.f : 0.f);
    int served = 0; float logps = 0.f;

    // ---- stage VH[g][n][d] (n zero-padded to 112), P pads, initial QV ----
    for (int i = t; i < 8*112*16; i += TDEC){
        int gg = i / 1792, r = i - gg*1792;
        int n = r >> 4, d = r & 15;
        sm[VH_OFF + gg*VGPP + n*VPITCH + d] =
            (n < NT) ? KVP[(mb + n)*384 + 128 + gg*16 + d] : 0.f;
    }
    for (int i = t; i < 8*PSTR; i += TDEC) sm[P_OFF + i] = 0.f;
    if (t >= 384) sm[QV_OFF + (t - 384)] = QA[mb*D128 + (t - 384)];
    __syncthreads();

    for (int s = 0; s < n_steps; ++s){
        // ==== P1: compat -> softmax -> PV (wave-internal, no barrier) ====
        float qk1 = 0.f, qk2 = 0.f;
        {
            const float4* qp = (const float4*)&sm[QV_OFF + g*16];
            #pragma unroll
            for (int j4 = 0; j4 < 4; ++j4){
                float4 q4 = qp[j4];
                qk1 += q4.x*k0[j4*4+0] + q4.y*k0[j4*4+1] + q4.z*k0[j4*4+2] + q4.w*k0[j4*4+3];
                qk2 += q4.x*k1[j4*4+0] + q4.y*k1[j4*4+1] + q4.z*k1[j4*4+2] + q4.w*k1[j4*4+3];
            }
        }
        float c1 = 0.25f*(qk1 + dyn*kwl1);
        if (m1 > 0.f) c1 = -1000000000.0f;
        float c2 = -1000000000.0f;
        if (hasB){
            float a = 0.25f*(qk2 + dyn*kwl2);
            c2 = (m2 > 0.f) ? -1000000000.0f : a;
        }
        float mx = wave_max64(fmaxf(c1, c2));
        float p1 = expf(c1 - mx);
        float p2v = hasB ? expf(c2 - mx) : 0.f;
        float ls = wave_sum64(p1 + p2v);
        sm[P_OFF + g*PSTR + l] = p1;
        if (hasB) sm[P_OFF + g*PSTR + 64 + l] = p2v;
        // same-wave DS ordering: write->read needs no __syncthreads
        float acc = 0.f;
        {
            const float4* pp = (const float4*)&sm[P_OFF + g*PSTR + qq*28];
            const float* vb = &sm[VH_OFF + g*VGPP + (qq*28)*VPITCH + d16];
            #pragma unroll
            for (int i4 = 0; i4 < 7; ++i4){
                float4 pv = pp[i4];
                acc += pv.x*vb[(i4*4+0)*VPITCH] + pv.y*vb[(i4*4+1)*VPITCH]
                     + pv.z*vb[(i4*4+2)*VPITCH] + pv.w*vb[(i4*4+3)*VPITCH];
            }
        }
        acc += __shfl_xor(acc, 16, 64);
        acc += __shfl_xor(acc, 32, 64);
        if (l < 16) sm[O_OFFS + g*16 + l] = acc / ls;

        // ==== P2: logit partials for dim-block g (own-wave O, no barrier) ====
        float lg1 = 0.f, lg2 = 0.f;
        {
            const float4* op = (const float4*)&sm[O_OFFS + g*16];
            #pragma unroll
            for (int j4 = 0; j4 < 4; ++j4){
                float4 o4 = op[j4];
                lg1 += o4.x*p2a[j4*4+0] + o4.y*p2a[j4*4+1] + o4.z*p2a[j4*4+2] + o4.w*p2a[j4*4+3];
                lg2 += o4.x*p2b[j4*4+0] + o4.y*p2b[j4*4+1] + o4.z*p2b[j4*4+2] + o4.w*p2b[j4*4+3];
            }
        }
        sm[LGH_OFF + g*104 + l] = lg1;
        if (hasB) sm[LGH_OFF + g*104 + 64 + l] = lg2;
        __syncthreads();                                   // B

        // ==== F: raw-score argmax (tanh monotone -> same winner), redundant per wave ====
        float s1v = 0.f;
        #pragma unroll
        for (int w = 0; w < 8; ++w) s1v += sm[LGH_OFF + w*104 + l];
        float s2v = 0.f;
        if (hasB){
            #pragma unroll
            for (int w = 0; w < 8; ++w) s2v += sm[LGH_OFF + w*104 + 64 + l];
        }
        float r1 = (m1 > 0.f) ? -3.0e38f : s1v;
        float r2 = hasB ? ((m2 > 0.f) ? -3.0e38f : s2v) : -3.3e38f;
        float bv = r1; int bix = l;
        if (r2 > bv){ bv = r2; bix = l + 64; }
        wave_argmax64(bv, bix);
        // QA row fetch for next step (waves 6,7): issue early, write QV before C
        float qreg = 0.f;
        if (t >= 384) qreg = QA[(mb + bix)*D128 + (t - 384)];
        // save pre-update state for wave0's shadow lse
        float m1o = m1, m2o = m2;
        bool keep_lp = (served < NT - 1);
        // bookkeeping (redundant, wave-uniform)
        float selv = (bix < 64) ? __shfl(dem1, bix, 64) : __shfl(dem2, bix - 64, 64);
        float vis  = (bix < 64) ? __shfl(mk1a, bix, 64) : __shfl(mk1b, bix - 64, 64);
        bool go = bix < nd;
        float dynN = go ? capfull : (dyn - selv);
        if (!go && vis == 0.f) served++;
        if (bix == l && l >= nd) mk1a = 1.f;
        if (hasB && bix == (l + 64)) mk1b = 1.f;
        bool done = served >= NT - nd;
        float depotf = (go && !done) ? 1.f : 0.f;
        dyn = dynN;
        m1 = fmaxf(mk1a, (dem1 > dyn) ? 1.f : 0.f);
        if (l < nd) m1 = depotf;
        m2 = fmaxf(mk1b, (dem2 > dyn) ? 1.f : 0.f);
        if ((l + 64) < nd) m2 = depotf;
        if (t >= 384) sm[QV_OFF + (t - 384)] = qreg;
        if (g == 0 && l == 0) out[(size_t)b*n_steps + s] = (float)bix;
        __syncthreads();                                   // C

        // ==== wave 0 shadow: true logits -> lse -> logp (hidden under other waves' P1) ====
        if (g == 0){
            float Lm = tanhf(bv * INV_D_CONST) * 10.0f / temp;
            float L1 = (m1o > 0.f) ? (-1000000000.0f / temp)
                                   : (tanhf(s1v * INV_D_CONST) * 10.0f / temp);
            float e1 = expf(L1 - Lm);
            float e2 = 0.f;
            if (hasB){
                float L2 = (m2o > 0.f) ? (-1000000000.0f / temp)
                                       : (tanhf(s2v * INV_D_CONST) * 10.0f / temp);
                e2 = expf(L2 - Lm);
            }
            float ss = wave_sum64(e1 + e2);
            if (keep_lp) logps += -logf(ss);
        }
    }
    if (t == 0) out[(size_t)gridDim.x*n_steps + b] = logps;
}

extern "C" void kernel_launch(void* const* d_in, const int* in_sizes, int n_in,
                              void* d_out, int out_size, void* d_ws, size_t ws_size,
                              hipStream_t stream) {
    const float* enc     = (const float*)d_in[0];
    const float* pool    = (const float*)d_in[1];
    const float* capv    = (const float*)d_in[2];
    const float* demand  = (const float*)d_in[3];
    const float* fc_w    = (const float*)d_in[4];
    const float* fc1_w   = (const float*)d_in[5];
    const float* attn_w  = (const float*)d_in[6];
    const float* attn_k  = (const float*)d_in[7];
    const float* attn_v  = (const float*)d_in[8];
    const float* attn_fc = (const float*)d_in[9];
    const float* prob_k  = (const float*)d_in[10];
    const void*  p_nd    = d_in[12];
    const void*  p_temp  = d_in[13];

    int B = in_sizes[1] / D128;          // pool is (B, D)
    int n_steps = out_size / B - 1;      // out = B*n_steps actions + B logps
    int M = B * NT;

    float* ws    = (float*)d_ws;
    float* Wcat  = ws;                               // 128*512
    float* wlast = Wcat + 128*512;                   // 128
    float* pq    = wlast + 128;                      // B*128
    float* KVP   = pq + (size_t)B*D128;              // M*384
    float* QA    = KVP + (size_t)M*384;              // M*128

    prep_w2<<<129, 512, 0, stream>>>(fc_w, attn_w, prob_k, attn_fc, attn_k, attn_v, Wcat, wlast);
    prep_pq<<<B, 128, 0, stream>>>(pool, fc1_w, attn_w, pq);
    dim3 ggrid((M + 63)/64, 8);
    gemm_prep<<<ggrid, 256, 0, stream>>>(enc, Wcat, pq, M, KVP, QA);

    decode<<<B, TDEC, 0, stream>>>(QA, KVP, wlast, demand, capv, p_nd, p_temp,
                                   n_steps, (float*)d_out);
}